// Round 12
// baseline (296.661 us; speedup 1.0000x reference)
//
#include <hip/hip_runtime.h>
#include <hip/hip_bf16.h>

// SNN EventProp LIF forward, 2 layers: 784 -> 1024 -> 256, T=100, B=256.
//
// Structure: LIF current I is LINEAR in the matmul results -> all T matmuls
// of a layer collapse into one batched sparse op + per-(b,n) streaming scan.
// Both matmul inputs are BINARY spikes (x ~5%; layer-1 spikes ~5e-6 rare),
// so each "GEMM" is a sparse gather-ADD of weight rows (fp32-exact).
//
// HARD-WON RULES:
//  - (r3+r4) never fuse the serial t-loop into a kernel with per-step
//    barriers/global-round-trips at 1 wave/SIMD. (r12 refines: fusion IS ok
//    when the per-step state is LDS/register-resident and barrier-free.)
//  - (r5) in-kernel compaction costs ~35 us; hoisted into prep.
//  - (r7) LDS-staging of the gather table LOSES (scalar ds_read_b32).
//  - (r8) data-dependent GLOBAL load-skipping LOSES; LDS-resident flags ok.
//  - (r9/r10) NONTEMPORAL C1 stores keep W1T L2/L1-resident: sparse1 ~130
//    -> <48 us (~85 TB/s effective, L1-assisted). scan1 must then batch its
//    C1 loads EXPLICITLY (compiler won't pipeline; VGPR_Count=8 -> 70 us).
//  - (r11) harness reset ops are a fixed ~80 us of every measurement.
//
//   prep    : precompact x rows -> (cnts, lists) + transpose W1, W2 (fused)
//   sparse1 : C1[25088,1024] = sum of W1T rows per list (8-deep float4 ILP,
//             nt stores)
//   scan1   : LIF scan, 14-batched loads, spikes exit as u64 ballot words
//   layer2  : FUSED gather+scan; all 99 mask rows preloaded to LDS, rare
//             W2T gathers, register LIF, nt out stores. No C2 round trip.
//
// ALPHA=0.8f, BETA=0.95f, 1-BETA=0.05f (exact float32 of the Python consts).

#define ALPHA_F 0.8f
#define BETA_F 0.95f
#define ONE_MINUS_BETA_F 0.05f

typedef float f4_nt __attribute__((ext_vector_type(4)));   // nt-store-capable

// Fused prep. Blocks [0,6272): precompact 4 rows each (one per wave).
// Blocks [6272,7072): transpose W1 32x32 tiles. Blocks [7072,7328): W2.
__global__ __launch_bounds__(256) void prep(const float* __restrict__ x,
                                            const float* __restrict__ W1,
                                            const float* __restrict__ W2,
                                            float* __restrict__ W1T,
                                            float* __restrict__ W2T,
                                            int* __restrict__ cnts,
                                            int* __restrict__ lists) {
    __shared__ float tile[32][33];
    const int bid = blockIdx.x;
    const int tid = threadIdx.x;

    if (bid < 6272) {
        // ---- precompact: one wave per x-row r = t*256+b (t=0..97) ----
        const int r = bid * 4 + (tid >> 6);
        const int lane = tid & 63;
        const int k0 = lane * 4;
        unsigned flags = 0;
        if (lane < 49) {   // 49 float4 = 196 * 4 = 784 floats
            float4 v = *(const float4*)(x + (size_t)r * 784 + k0);
            flags = (v.x != 0.0f ? 1u : 0u) | (v.y != 0.0f ? 2u : 0u) |
                    (v.z != 0.0f ? 4u : 0u) | (v.w != 0.0f ? 8u : 0u);
        }
        const unsigned long long m0 = __ballot(flags & 1u);
        const unsigned long long m1 = __ballot(flags & 2u);
        const unsigned long long m2 = __ballot(flags & 4u);
        const unsigned long long m3 = __ballot(flags & 8u);
        const int c0 = __popcll(m0), c1 = __popcll(m1), c2 = __popcll(m2);
        const unsigned long long lm = ((unsigned long long)1 << lane) - 1;
        int* lrow = lists + (size_t)r * 160;
        if (flags & 1u) lrow[__popcll(m0 & lm)] = k0 + 0;
        if (flags & 2u) lrow[c0 + __popcll(m1 & lm)] = k0 + 1;
        if (flags & 4u) lrow[c0 + c1 + __popcll(m2 & lm)] = k0 + 2;
        if (flags & 8u) lrow[c0 + c1 + c2 + __popcll(m3 & lm)] = k0 + 3;
        if (lane == 0) cnts[r] = c0 + c1 + c2 + __popcll(m3);
    } else {
        // ---- transpose: WT[k*N+n] = W[n*K+k] ----
        const float* W; float* WT; int N, K, tk, tn;
        if (bid < 7072) {
            W = W1; WT = W1T; N = 1024; K = 784;
            const int i = bid - 6272; tk = i % 25; tn = i / 25;   // 25 x 32
        } else {
            W = W2; WT = W2T; N = 256; K = 1024;
            const int i = bid - 7072; tk = i % 32; tn = i / 32;   // 32 x 8
        }
        const int k0 = tk * 32, n0 = tn * 32;
        const int tx = tid & 31, ty = tid >> 5;   // 32 x 8
#pragma unroll
        for (int r = 0; r < 4; ++r) {
            int n = n0 + ty + r * 8, k = k0 + tx;
            if (n < N && k < K) tile[ty + r * 8][tx] = W[(size_t)n * K + k];
        }
        __syncthreads();
#pragma unroll
        for (int r = 0; r < 4; ++r) {
            int k = k0 + ty + r * 8, n = n0 + tx;
            if (k < K && n < N) WT[(size_t)k * N + n] = tile[tx][ty + r * 8];
        }
    }
}

// Layer-1 gather. One block per row; thread owns 4 contiguous cols;
// cnt/list accesses block-uniform -> scalar loads; loop is pure dwordx4
// gather + adds, 8-deep ILP. C1 store is NONTEMPORAL (write-once stream --
// keeps W1T resident in per-XCD L2/L1; measured ~2-3x sparse1 speedup).
__global__ __launch_bounds__(256) void sparse1(const int* __restrict__ cnts,
                                               const int* __restrict__ lists,
                                               const float* __restrict__ W1T,
                                               float* __restrict__ C1) {
    const int tid = threadIdx.x;
    const int row = blockIdx.x;
    const int n = cnts[row];
    const int* lst = lists + (size_t)row * 160;
    const float* wbase = W1T + tid * 4;
    float4 acc = {0.0f, 0.0f, 0.0f, 0.0f};
    int i = 0;
    for (; i + 8 <= n; i += 8) {
        float4 w0 = *(const float4*)(wbase + (size_t)lst[i + 0] * 1024);
        float4 w1 = *(const float4*)(wbase + (size_t)lst[i + 1] * 1024);
        float4 w2 = *(const float4*)(wbase + (size_t)lst[i + 2] * 1024);
        float4 w3 = *(const float4*)(wbase + (size_t)lst[i + 3] * 1024);
        float4 w4 = *(const float4*)(wbase + (size_t)lst[i + 4] * 1024);
        float4 w5 = *(const float4*)(wbase + (size_t)lst[i + 5] * 1024);
        float4 w6 = *(const float4*)(wbase + (size_t)lst[i + 6] * 1024);
        float4 w7 = *(const float4*)(wbase + (size_t)lst[i + 7] * 1024);
        acc.x += ((w0.x + w1.x) + (w2.x + w3.x)) + ((w4.x + w5.x) + (w6.x + w7.x));
        acc.y += ((w0.y + w1.y) + (w2.y + w3.y)) + ((w4.y + w5.y) + (w6.y + w7.y));
        acc.z += ((w0.z + w1.z) + (w2.z + w3.z)) + ((w4.z + w5.z) + (w6.z + w7.z));
        acc.w += ((w0.w + w1.w) + (w2.w + w3.w)) + ((w4.w + w5.w) + (w6.w + w7.w));
    }
    for (; i < n; ++i) {
        float4 w0 = *(const float4*)(wbase + (size_t)lst[i] * 1024);
        acc.x += w0.x; acc.y += w0.y; acc.z += w0.z; acc.w += w0.w;
    }
    f4_nt o = {acc.x, acc.y, acc.z, acc.w};
    __builtin_nontemporal_store(o, (f4_nt*)(C1 + (size_t)row * 1024 + tid * 4));
}

// Layer-1 scan: one col per thread (262144 threads = 4 waves/SIMD).
// Loads in EXPLICIT batches of 14 (98 = 7*14): all 14 issued before the
// recurrence consumes them -> 56 KB in flight per CU -> HBM-BW-bound.
// Spikes exit as ballot-packed u64 words: S1b[t*4096 + (b*1024+n)/64].
__global__ __launch_bounds__(256) void scan1(const float* __restrict__ C1,
                                             unsigned long long* __restrict__ S1b) {
    const int idx = blockIdx.x * 256 + threadIdx.x;   // 0..262143
    const int word = idx >> 6;
    const int lane = threadIdx.x & 63;
    if (lane == 0) S1b[word] = 0ull;                   // t = 0
    float I = 0.0f, V = 0.0f;
    for (int t0 = 1; t0 <= 85; t0 += 14) {             // t0 = 1,15,...,85
        float c[14];
#pragma unroll
        for (int j = 0; j < 14; ++j)
            c[j] = C1[(size_t)(t0 - 1 + j) * 262144 + idx];
#pragma unroll
        for (int j = 0; j < 14; ++j) {
            I = ALPHA_F * I + c[j];
            float Vp = BETA_F * V + ONE_MINUS_BETA_F * I;
            const bool sp = Vp > 1.0f;
            unsigned long long m = __ballot(sp);
            V = sp ? 0.0f : Vp;
            if (lane == 0) S1b[(size_t)(t0 + j) * 4096 + word] = m;
        }
    }
}

// Layer 2 FUSED: one block per batch b, thread = n2. All 99 mask rows
// (99*16 u64 = 12.7 KB) preloaded to LDS in one coalesced burst; per t the
// block walks the (mostly zero) masks -- LDS-resident tests, no global
// round trip -- gathers W2T[k][n2] only on the rare spike, runs the LIF
// recurrence in registers, nt-stores out. Gather order (j asc, bit asc)
// and arithmetic identical to the split sparse2+scan2.
__global__ __launch_bounds__(256) void layer2(const unsigned long long* __restrict__ S1b,
                                              const float* __restrict__ W2T,
                                              float* __restrict__ out) {
    __shared__ unsigned long long masks[99 * 16];      // 12,672 B
    const int b = blockIdx.x;
    const int tid = threadIdx.x;
    for (int i = tid; i < 99 * 16; i += 256) {
        const int tt = i >> 4, j = i & 15;             // S1 row tt, word j
        masks[i] = S1b[(size_t)tt * 4096 + b * 16 + j];
    }
    __syncthreads();

    __builtin_nontemporal_store(0.0f, out + b * 256 + tid);   // t = 0
    float I = 0.0f, V = 0.0f;
    for (int t = 1; t <= 99; ++t) {
        const unsigned long long* mrow = &masks[(t - 1) * 16];
        float c = 0.0f;
#pragma unroll 1
        for (int j = 0; j < 16; ++j) {
            unsigned long long m = mrow[j];
            while (m) {                                 // block-uniform walk
                const int bit = __ffsll((long long)m) - 1;
                m &= m - 1;
                c += W2T[(size_t)(j * 64 + bit) * 256 + tid];
            }
        }
        I = ALPHA_F * I + c;
        float Vp = BETA_F * V + ONE_MINUS_BETA_F * I;
        float s = (Vp > 1.0f) ? 1.0f : 0.0f;
        V = (1.0f - s) * Vp;
        __builtin_nontemporal_store(s, out + (size_t)t * 65536 + b * 256 + tid);
    }
}

extern "C" void kernel_launch(void* const* d_in, const int* in_sizes, int n_in,
                              void* d_out, int out_size, void* d_ws, size_t ws_size,
                              hipStream_t stream) {
    const float* x  = (const float*)d_in[0];   // [100,256,784] binary
    const float* W1 = (const float*)d_in[1];   // [1024,784]
    const float* W2 = (const float*)d_in[2];   // [256,1024]
    float* out = (float*)d_out;                // [100,256,256]

    // Workspace (~126 MB, offsets 16B-aligned):
    //   C1    @ 0          : 25088*1024*4 = 102,760,448
    //   S1b   @ 102760448  : 99*4096*8    =   3,244,032
    //   W1T   @ 106004480  : 784*1024*4   =   3,211,264
    //   W2T   @ 109215744  : 1024*256*4   =   1,048,576
    //   cnts  @ 110264320  : 25088*4      =     100,352
    //   lists @ 110364672  : 25088*160*4  =  16,056,320   (end 126,420,992)
    char* ws = (char*)d_ws;
    float* C1 = (float*)ws;
    unsigned long long* S1b = (unsigned long long*)(ws + 102760448);
    float* W1T = (float*)(ws + 106004480);
    float* W2T = (float*)(ws + 109215744);
    int* cnts  = (int*)(ws + 110264320);
    int* lists = (int*)(ws + 110364672);

    prep<<<7328, 256, 0, stream>>>(x, W1, W2, W1T, W2T, cnts, lists);
    sparse1<<<25088, 256, 0, stream>>>(cnts, lists, W1T, C1);
    scan1<<<1024, 256, 0, stream>>>(C1, S1b);
    layer2<<<256, 256, 0, stream>>>(S1b, W2T, out);
}

// Round 13
// 211.858 us; speedup vs baseline: 1.4003x; 1.4003x over previous
//
#include <hip/hip_runtime.h>
#include <hip/hip_bf16.h>

// SNN EventProp LIF forward, 2 layers: 784 -> 1024 -> 256, T=100, B=256.
//
// Structure: LIF current I is LINEAR in the matmul results -> all T matmuls
// of a layer collapse into one batched sparse op + per-(b,n) streaming scan.
// Both matmul inputs are BINARY spikes (x ~5%; layer-1 spikes ~5e-6 rare),
// so each "GEMM" is a sparse gather-ADD of weight rows (fp32-exact).
//
// HARD-WON RULES:
//  - (r3/r4/r12) a ~1-block/CU kernel with a 99-step dependent chain is
//    latency-bound regardless of data residency (global/L2/LDS): fusing the
//    t-loop into gather kernels lost 2-5x THREE times. Scans must be
//    separate streaming kernels with explicitly batched independent loads.
//  - (r5) in-kernel compaction costs ~35 us; hoisted into prep.
//  - (r7) LDS-staging of the gather table LOSES (scalar ds_read_b32).
//  - (r8) data-dependent load-skipping in scan kernels LOSES (+20 us).
//  - (r9/r10) NONTEMPORAL C1 stores keep W1T L2-resident: sparse1 ~130 ->
//    <48 us. scan1 must then batch C1 loads EXPLICITLY (compiler won't
//    pipeline; VGPR_Count=8 -> one exposed HBM round trip per t = 70 us).
//  - (r12) C2's 26 MB round trip is L2/L3-resident (FETCH 1.6 MB) -- it was
//    never an HBM cost. Split sparse2+scan2 ~20 us is the floor there.
//  - (r11) harness reset ops are a fixed ~80 us of every measurement.
//
//   prep    : precompact x rows (nt loads) -> (cnts, lists) + transposes
//   sparse1 : C1[25088,1024] = sum of W1T rows per list (8-deep float4 ILP,
//             nt stores)
//   scan1   : LIF scan, 14-batched loads, spikes exit as u64 ballot words
//   sparse2 : C2[25344,256]; 16 uniform u64 mask words/row, SALU bit-walk
//   scan2   : out[100,256,256], 9-batched loads, nt stores
//
// ALPHA=0.8f, BETA=0.95f, 1-BETA=0.05f (exact float32 of the Python consts).

#define ALPHA_F 0.8f
#define BETA_F 0.95f
#define ONE_MINUS_BETA_F 0.05f

typedef float f4_nt __attribute__((ext_vector_type(4)));   // nt-capable vec4

// Fused prep. Blocks [0,6272): precompact 4 rows each (one per wave).
// Blocks [6272,7072): transpose W1 32x32 tiles. Blocks [7072,7328): W2.
__global__ __launch_bounds__(256) void prep(const float* __restrict__ x,
                                            const float* __restrict__ W1,
                                            const float* __restrict__ W2,
                                            float* __restrict__ W1T,
                                            float* __restrict__ W2T,
                                            int* __restrict__ cnts,
                                            int* __restrict__ lists) {
    __shared__ float tile[32][33];
    const int bid = blockIdx.x;
    const int tid = threadIdx.x;

    if (bid < 6272) {
        // ---- precompact: one wave per x-row r = t*256+b (t=0..97) ----
        const int r = bid * 4 + (tid >> 6);
        const int lane = tid & 63;
        const int k0 = lane * 4;
        unsigned flags = 0;
        if (lane < 49) {   // 49 float4 = 196 * 4 = 784 floats
            f4_nt v = __builtin_nontemporal_load(
                (const f4_nt*)(x + (size_t)r * 784 + k0));   // read-once: keep L2 clean
            flags = (v.x != 0.0f ? 1u : 0u) | (v.y != 0.0f ? 2u : 0u) |
                    (v.z != 0.0f ? 4u : 0u) | (v.w != 0.0f ? 8u : 0u);
        }
        const unsigned long long m0 = __ballot(flags & 1u);
        const unsigned long long m1 = __ballot(flags & 2u);
        const unsigned long long m2 = __ballot(flags & 4u);
        const unsigned long long m3 = __ballot(flags & 8u);
        const int c0 = __popcll(m0), c1 = __popcll(m1), c2 = __popcll(m2);
        const unsigned long long lm = ((unsigned long long)1 << lane) - 1;
        int* lrow = lists + (size_t)r * 160;
        if (flags & 1u) lrow[__popcll(m0 & lm)] = k0 + 0;
        if (flags & 2u) lrow[c0 + __popcll(m1 & lm)] = k0 + 1;
        if (flags & 4u) lrow[c0 + c1 + __popcll(m2 & lm)] = k0 + 2;
        if (flags & 8u) lrow[c0 + c1 + c2 + __popcll(m3 & lm)] = k0 + 3;
        if (lane == 0) cnts[r] = c0 + c1 + c2 + __popcll(m3);
    } else {
        // ---- transpose: WT[k*N+n] = W[n*K+k] ----
        const float* W; float* WT; int N, K, tk, tn;
        if (bid < 7072) {
            W = W1; WT = W1T; N = 1024; K = 784;
            const int i = bid - 6272; tk = i % 25; tn = i / 25;   // 25 x 32
        } else {
            W = W2; WT = W2T; N = 256; K = 1024;
            const int i = bid - 7072; tk = i % 32; tn = i / 32;   // 32 x 8
        }
        const int k0 = tk * 32, n0 = tn * 32;
        const int tx = tid & 31, ty = tid >> 5;   // 32 x 8
#pragma unroll
        for (int r = 0; r < 4; ++r) {
            int n = n0 + ty + r * 8, k = k0 + tx;
            if (n < N && k < K) tile[ty + r * 8][tx] = W[(size_t)n * K + k];
        }
        __syncthreads();
#pragma unroll
        for (int r = 0; r < 4; ++r) {
            int k = k0 + ty + r * 8, n = n0 + tx;
            if (k < K && n < N) WT[(size_t)k * N + n] = tile[tx][ty + r * 8];
        }
    }
}

// Layer-1 gather. One block per row; thread owns 4 contiguous cols;
// cnt/list accesses block-uniform -> scalar loads; loop is pure dwordx4
// gather + adds, 8-deep ILP. C1 store is NONTEMPORAL (write-once stream --
// keeps W1T resident in per-XCD L2/L1; measured ~2-3x sparse1 speedup).
__global__ __launch_bounds__(256) void sparse1(const int* __restrict__ cnts,
                                               const int* __restrict__ lists,
                                               const float* __restrict__ W1T,
                                               float* __restrict__ C1) {
    const int tid = threadIdx.x;
    const int row = blockIdx.x;
    const int n = cnts[row];
    const int* lst = lists + (size_t)row * 160;
    const float* wbase = W1T + tid * 4;
    float4 acc = {0.0f, 0.0f, 0.0f, 0.0f};
    int i = 0;
    for (; i + 8 <= n; i += 8) {
        float4 w0 = *(const float4*)(wbase + (size_t)lst[i + 0] * 1024);
        float4 w1 = *(const float4*)(wbase + (size_t)lst[i + 1] * 1024);
        float4 w2 = *(const float4*)(wbase + (size_t)lst[i + 2] * 1024);
        float4 w3 = *(const float4*)(wbase + (size_t)lst[i + 3] * 1024);
        float4 w4 = *(const float4*)(wbase + (size_t)lst[i + 4] * 1024);
        float4 w5 = *(const float4*)(wbase + (size_t)lst[i + 5] * 1024);
        float4 w6 = *(const float4*)(wbase + (size_t)lst[i + 6] * 1024);
        float4 w7 = *(const float4*)(wbase + (size_t)lst[i + 7] * 1024);
        acc.x += ((w0.x + w1.x) + (w2.x + w3.x)) + ((w4.x + w5.x) + (w6.x + w7.x));
        acc.y += ((w0.y + w1.y) + (w2.y + w3.y)) + ((w4.y + w5.y) + (w6.y + w7.y));
        acc.z += ((w0.z + w1.z) + (w2.z + w3.z)) + ((w4.z + w5.z) + (w6.z + w7.z));
        acc.w += ((w0.w + w1.w) + (w2.w + w3.w)) + ((w4.w + w5.w) + (w6.w + w7.w));
    }
    for (; i < n; ++i) {
        float4 w0 = *(const float4*)(wbase + (size_t)lst[i] * 1024);
        acc.x += w0.x; acc.y += w0.y; acc.z += w0.z; acc.w += w0.w;
    }
    f4_nt o = {acc.x, acc.y, acc.z, acc.w};
    __builtin_nontemporal_store(o, (f4_nt*)(C1 + (size_t)row * 1024 + tid * 4));
}

// Layer-1 scan: one col per thread (262144 threads = 4 waves/SIMD).
// Loads in EXPLICIT batches of 14 (98 = 7*14): all 14 issued before the
// recurrence consumes them -> 56 KB in flight per CU -> HBM-BW-bound.
// Spikes exit as ballot-packed u64 words: S1b[t*4096 + (b*1024+n)/64].
__global__ __launch_bounds__(256) void scan1(const float* __restrict__ C1,
                                             unsigned long long* __restrict__ S1b) {
    const int idx = blockIdx.x * 256 + threadIdx.x;   // 0..262143
    const int word = idx >> 6;
    const int lane = threadIdx.x & 63;
    if (lane == 0) S1b[word] = 0ull;                   // t = 0
    float I = 0.0f, V = 0.0f;
    for (int t0 = 1; t0 <= 85; t0 += 14) {             // t0 = 1,15,...,85
        float c[14];
#pragma unroll
        for (int j = 0; j < 14; ++j)
            c[j] = C1[(size_t)(t0 - 1 + j) * 262144 + idx];
#pragma unroll
        for (int j = 0; j < 14; ++j) {
            I = ALPHA_F * I + c[j];
            float Vp = BETA_F * V + ONE_MINUS_BETA_F * I;
            const bool sp = Vp > 1.0f;
            unsigned long long m = __ballot(sp);
            V = sp ? 0.0f : Vp;
            if (lane == 0) S1b[(size_t)(t0 + j) * 4096 + word] = m;
        }
    }
}

// Layer-2 gather: one wave per row r = t*256+b (25344 rows), 4 waves/block.
// Mask row = 16 uniform u64 words; SALU bit-walk; one float4 gather per
// spike. Stores stay CACHED (scan2 reads C2 right after; r12 showed this
// round trip is fully L2/L3-resident).
__global__ __launch_bounds__(256) void sparse2(const unsigned long long* __restrict__ S1b,
                                               const float* __restrict__ W2T,
                                               float* __restrict__ C2) {
    const int r = __builtin_amdgcn_readfirstlane(blockIdx.x * 4 + (threadIdx.x >> 6));
    const int lane = threadIdx.x & 63;
    const unsigned long long* mrow = S1b + (size_t)r * 16;
    float4 acc = {0, 0, 0, 0};
#pragma unroll 1
    for (int j = 0; j < 16; ++j) {
        unsigned long long m = mrow[j];
        while (m) {
            const int bit = __ffsll((long long)m) - 1;
            m &= m - 1;
            const int k = j * 64 + bit;
            float4 w = *(const float4*)(W2T + (size_t)k * 256 + lane * 4);
            acc.x += w.x; acc.y += w.y; acc.z += w.z; acc.w += w.w;
        }
    }
    *(float4*)(C2 + (size_t)r * 256 + lane * 4) = acc;
}

// Layer-2 scan: one thread per (b,n2). EXPLICIT 9-batched loads (99 = 11*9),
// unconditional (r8 lesson). out stores nontemporal (never re-read).
__global__ __launch_bounds__(256) void scan2(const float* __restrict__ C2,
                                             float* __restrict__ out) {
    const int idx = blockIdx.x * 256 + threadIdx.x;
    __builtin_nontemporal_store(0.0f, out + idx);      // t = 0
    float I = 0.0f, V = 0.0f;
    for (int t0 = 1; t0 <= 91; t0 += 9) {              // t0 = 1,10,...,91
        float c[9];
#pragma unroll
        for (int j = 0; j < 9; ++j)
            c[j] = C2[(size_t)(t0 - 1 + j) * 65536 + idx];
#pragma unroll
        for (int j = 0; j < 9; ++j) {
            I = ALPHA_F * I + c[j];
            float Vp = BETA_F * V + ONE_MINUS_BETA_F * I;
            float s = (Vp > 1.0f) ? 1.0f : 0.0f;
            V = (1.0f - s) * Vp;
            __builtin_nontemporal_store(s, out + (size_t)(t0 + j) * 65536 + idx);
        }
    }
}

extern "C" void kernel_launch(void* const* d_in, const int* in_sizes, int n_in,
                              void* d_out, int out_size, void* d_ws, size_t ws_size,
                              hipStream_t stream) {
    const float* x  = (const float*)d_in[0];   // [100,256,784] binary
    const float* W1 = (const float*)d_in[1];   // [1024,784]
    const float* W2 = (const float*)d_in[2];   // [256,1024]
    float* out = (float*)d_out;                // [100,256,256]

    // Workspace (~126 MB, offsets 16B-aligned):
    //   C1    @ 0          : 25088*1024*4 = 102,760,448   (C2 aliases C1)
    //   S1b   @ 102760448  : 99*4096*8    =   3,244,032
    //   W1T   @ 106004480  : 784*1024*4   =   3,211,264
    //   W2T   @ 109215744  : 1024*256*4   =   1,048,576
    //   cnts  @ 110264320  : 25088*4      =     100,352
    //   lists @ 110364672  : 25088*160*4  =  16,056,320   (end 126,420,992)
    char* ws = (char*)d_ws;
    float* C1 = (float*)ws;
    unsigned long long* S1b = (unsigned long long*)(ws + 102760448);
    float* W1T = (float*)(ws + 106004480);
    float* W2T = (float*)(ws + 109215744);
    int* cnts  = (int*)(ws + 110264320);
    int* lists = (int*)(ws + 110364672);
    float* C2 = C1;

    prep<<<7328, 256, 0, stream>>>(x, W1, W2, W1T, W2T, cnts, lists);
    sparse1<<<25088, 256, 0, stream>>>(cnts, lists, W1T, C1);
    scan1<<<1024, 256, 0, stream>>>(C1, S1b);
    sparse2<<<25344 / 4, 256, 0, stream>>>(S1b, W2T, C2);
    scan2<<<256, 256, 0, stream>>>(C2, out);
}